// Round 11
// baseline (877.467 us; speedup 1.0000x reference)
//
#include <hip/hip_runtime.h>

// QRNN fo-pool: T=65536, E=512, H=512 (kernel_size=2)
// gates[T,1536] = concat(x, shift(x)) @ W + b ; z=tanh, f,o=sigmoid
// c_t = f_t c_{t-1} + (1-f_t) z_t ; h_t = o_t c_t
// out = [hiddens (T*512) | h_last (512) | c_last (512)]  (f32)

#define T_LEN 65536
#define H3    1536
#define LC    64
#define NCHUNK 1024

typedef float f32x4 __attribute__((ext_vector_type(4)));
typedef short bf16x8 __attribute__((ext_vector_type(8)));

__device__ __forceinline__ unsigned short f2bf(float f) {
    unsigned int x = __builtin_bit_cast(unsigned int, f);
    x += 0x7fffu + ((x >> 16) & 1u);
    return (unsigned short)(x >> 16);
}
__device__ __forceinline__ float bf2f(unsigned short u) {
    return __builtin_bit_cast(float, ((unsigned int)u) << 16);
}
// fast sigmoid/tanh: v_exp_f32 (exp2) + v_rcp_f32, ~1ulp each — far below bf16 grid
__device__ __forceinline__ float fsig(float x) {
    return __builtin_amdgcn_rcpf(1.f + __builtin_amdgcn_exp2f(-1.44269504f * x));
}
__device__ __forceinline__ float ftanh(float x) {
    return 2.f * __builtin_amdgcn_rcpf(1.f + __builtin_amdgcn_exp2f(-2.88539008f * x)) - 1.f;
}

__device__ __forceinline__ void gload_lds16(const void* g, void* l) {
    __builtin_amdgcn_global_load_lds((const __attribute__((address_space(1))) void*)g,
                                     (__attribute__((address_space(3))) void*)l, 16, 0, 0);
}

#define VM6()   asm volatile("s_waitcnt vmcnt(6)" ::: "memory")
#define VM0()   asm volatile("s_waitcnt vmcnt(0)" ::: "memory")
#define BARX()  __builtin_amdgcn_s_barrier()

// ---- prep: x (f32) -> bf16 with 512-element zero prefix ------------------
__global__ void prep_x(const float* __restrict__ x, unsigned short* __restrict__ xp) {
    const long long nq = (512LL + (long long)T_LEN * 512) / 4;
    for (long long q = (long long)blockIdx.x * blockDim.x + threadIdx.x; q < nq;
         q += (long long)gridDim.x * blockDim.x) {
        ushort4 u;
        if (q < 128) {
            u.x = 0; u.y = 0; u.z = 0; u.w = 0;
        } else {
            const float4 v = *reinterpret_cast<const float4*>(x + q * 4 - 512);
            u.x = f2bf(v.x); u.y = f2bf(v.y); u.z = f2bf(v.z); u.w = f2bf(v.w);
        }
        *reinterpret_cast<ushort4*>(xp + q * 4) = u;
    }
}

// ---- prep: W [1024,1536] f32 -> Wt [1536,1024] bf16 ----------------------
__global__ void prep_w(const float* __restrict__ W, unsigned short* __restrict__ Wt) {
    const int n_el = 1024 * H3;
    for (int i = blockIdx.x * blockDim.x + threadIdx.x; i < n_el;
         i += gridDim.x * blockDim.x) {
        const int k = i / H3, n = i - k * H3;
        Wt[n * 1024 + k] = f2bf(W[i]);
    }
}

// ---- GEMM: 128Mx256N tile, BK=32, 4 waves of 64x128, depth-2 pipeline ----
// (Round-7 kernel, verbatim: best measured 253 µs / MfmaUtil 37%.)
__global__ __launch_bounds__(256, 2) void gemm_gates(
    const unsigned short* __restrict__ xp,
    const unsigned short* __restrict__ Wt,
    const float* __restrict__ bias,
    unsigned short* __restrict__ zfo)
{
    __shared__ unsigned short Alds[3][128 * 32];
    __shared__ unsigned short Blds[3][256 * 32];

    const int tid  = threadIdx.x;
    const int lane = tid & 63;
    const int w    = tid >> 6;           // wave 0..3
    const int wm   = w >> 1, wn = w & 1; // 2x2 wave grid, each 64M x 128N

    // XCD-chunked swizzle (T1): 3072 blocks, 384/XCD; the 6 blocks sharing
    // an A-panel land consecutively on ONE XCD; B (3 MB) L2-resident.
    const int flat = blockIdx.y * gridDim.x + blockIdx.x;   // 0..3071
    const int idx  = (flat & 7) * 384 + (flat >> 3);
    const int nb   = (idx % 6) * 256;                       // N base (0..1280)
    const long long t0 = (long long)(idx / 6) * 128;        // M base (time rows)

    // staging geometry: wave-uniform LDS dest + lane*16B; pre-swizzled source col
    const int srow_l = lane >> 2;                               // 0..15
    const int scol   = (((lane & 3) ^ ((lane >> 3) & 3)) * 8);  // swizzled col (elems)

    const unsigned short* gA = xp + (t0 + w * 16 + srow_l) * 512 + 512 + scol;
    const unsigned short* gB = Wt + (long long)(nb + w * 16 + srow_l) * 1024 + scol;

    auto stage = [&](unsigned short* Al, unsigned short* Bl) {
        gload_lds16(gA,              Al + (w * 16) * 32);
        gload_lds16(gA + 64 * 512,   Al + (64 + w * 16) * 32);
        gload_lds16(gB,              Bl + (w * 16) * 32);
        gload_lds16(gB + 64 * 1024,  Bl + (64 + w * 16) * 32);
        gload_lds16(gB + 128 * 1024, Bl + (128 + w * 16) * 32);
        gload_lds16(gB + 192 * 1024, Bl + (192 + w * 16) * 32);
    };

    // fragment read geometry (swizzled read matches staged involution)
    const int arow  = lane & 15;
    const int swzco = (((lane >> 4) ^ ((arow >> 1) & 3)) * 8);

    f32x4 acc[4][8] = {};

    auto compute = [&](const unsigned short* Al, const unsigned short* Bl) {
        bf16x8 af[4], bfr[8];
        #pragma unroll
        for (int m = 0; m < 4; ++m)
            af[m] = *reinterpret_cast<const bf16x8*>(Al + (wm * 64 + m * 16 + arow) * 32 + swzco);
        #pragma unroll
        for (int n = 0; n < 8; ++n)
            bfr[n] = *reinterpret_cast<const bf16x8*>(Bl + (wn * 128 + n * 16 + arow) * 32 + swzco);
        #pragma unroll
        for (int n = 0; n < 8; ++n)
            #pragma unroll
            for (int m = 0; m < 4; ++m)
                acc[m][n] = __builtin_amdgcn_mfma_f32_16x16x32_bf16(af[m], bfr[n], acc[m][n], 0, 0, 0);
    };

    // prologue: stage tiles 0 (buf0), 1 (buf1); wait 6 oldest = tile0 done
    stage(Alds[0], Blds[0]); gA += 32; gB += 32;
    stage(Alds[1], Blds[1]); gA += 32; gB += 32;
    VM6();
    BARX();

    // main: kt = 0..29 in groups of 3 (buffer indices compile-time)
    for (int kt = 0; kt < 30; kt += 3) {
        {   // kt: stages tile kt+2 -> buf2; computes buf0
            stage(Alds[2], Blds[2]);
            gA += (kt + 2 == 15) ? -992 : 32;  gB += 32;
            compute(Alds[0], Blds[0]);
            VM6();                                            // tile kt+1 landed
            BARX();
        }
        {   // kt+1: stages tile kt+3 -> buf0; computes buf1
            stage(Alds[0], Blds[0]);
            gA += (kt + 3 == 15) ? -992 : 32;  gB += 32;
            compute(Alds[1], Blds[1]);
            VM6();
            BARX();
        }
        {   // kt+2: stages tile kt+4 -> buf1; computes buf2
            stage(Alds[1], Blds[1]);
            gA += (kt + 4 == 15) ? -992 : 32;  gB += 32;
            compute(Alds[2], Blds[2]);
            VM6();
            BARX();
        }
    }
    // kt=30: compute buf0 (tile30); drain tile31; kt=31: compute buf1
    compute(Alds[0], Blds[0]);
    VM0();
    BARX();
    compute(Alds[1], Blds[1]);

    // epilogue: bias + activation (cls uniform per block: nb multiple of 256)
    const int cls = nb >> 9;             // 0=z(tanh), 1=f, 2=o (sigmoid)
    #pragma unroll
    for (int n = 0; n < 8; ++n) {
        const int col = nb + wn * 128 + n * 16 + arow;
        const float bn_ = bias[col];
        #pragma unroll
        for (int m = 0; m < 4; ++m) {
            const long long row0 = t0 + wm * 64 + m * 16 + (lane >> 4) * 4;
            #pragma unroll
            for (int j = 0; j < 4; ++j) {
                float v = acc[m][n][j] + bn_;
                v = (cls == 0) ? ftanh(v) : fsig(v);
                zfo[(row0 + j) * H3 + col] = f2bf(v);
            }
        }
    }
}

// ---- single-pass scan with decoupled lookback -----------------------------
// 1024 blocks (one per 64-step chunk) x 128 threads (4 ch each).
// Phase 1: local scan (carry 0) -> aggregate (P,L); publish status=1 (release).
// Lookback: walk j=b-1.. consuming aggregates until a published prefix
// (status=2); spin only while status[j]==0. Publish own inclusive prefix.
// Phase 2: replay with carry (z,f L2-hot), write h = o*c.
__global__ __launch_bounds__(128) void scan_fused(
    const unsigned short* __restrict__ zfo,
    float* __restrict__ aggP, float* __restrict__ aggL,
    float* __restrict__ pref, int* __restrict__ status,
    float* __restrict__ out)
{
    const int b   = blockIdx.x;
    const int c4  = threadIdx.x;              // 0..127
    const int chb = c4 * 4;
    const unsigned short* base = zfo + (long long)b * LC * H3 + chb;

    // phase 1: local scan
    float c[4] = {0.f, 0.f, 0.f, 0.f};
    float p[4] = {1.f, 1.f, 1.f, 1.f};
    for (int t = 0; t < LC; ++t) {
        const unsigned short* row = base + t * H3;
        const ushort4 uz = *reinterpret_cast<const ushort4*>(row);
        const ushort4 uf = *reinterpret_cast<const ushort4*>(row + 512);
        const float z[4] = {bf2f(uz.x), bf2f(uz.y), bf2f(uz.z), bf2f(uz.w)};
        const float f[4] = {bf2f(uf.x), bf2f(uf.y), bf2f(uf.z), bf2f(uf.w)};
        #pragma unroll
        for (int j = 0; j < 4; ++j) {
            c[j] = fmaf(f[j], c[j] - z[j], z[j]);
            p[j] *= f[j];
        }
    }

    float C[4];
    if (b == 0) {
        #pragma unroll
        for (int j = 0; j < 4; ++j) pref[chb + j] = c[j];
        __threadfence();
        __syncthreads();
        if (c4 == 0)
            __hip_atomic_store(&status[0], 2, __ATOMIC_RELEASE, __HIP_MEMORY_SCOPE_AGENT);
        C[0] = C[1] = C[2] = C[3] = 0.f;
    } else {
        #pragma unroll
        for (int j = 0; j < 4; ++j) {
            aggP[b * 512 + chb + j] = p[j];
            aggL[b * 512 + chb + j] = c[j];
        }
        __threadfence();
        __syncthreads();
        if (c4 == 0)
            __hip_atomic_store(&status[b], 1, __ATOMIC_RELEASE, __HIP_MEMORY_SCOPE_AGENT);

        // lookback
        __shared__ int st;
        float Pa[4] = {1.f, 1.f, 1.f, 1.f};
        float La[4] = {0.f, 0.f, 0.f, 0.f};
        int j = b - 1;
        for (;;) {
            if (c4 == 0) {
                int s;
                do {
                    s = __hip_atomic_load(&status[j], __ATOMIC_ACQUIRE, __HIP_MEMORY_SCOPE_AGENT);
                } while (s == 0);
                st = s;
            }
            __syncthreads();
            const int s = st;
            if (s == 2) {
                #pragma unroll
                for (int k = 0; k < 4; ++k)
                    C[k] = fmaf(Pa[k], pref[j * 512 + chb + k], La[k]);
                break;
            }
            #pragma unroll
            for (int k = 0; k < 4; ++k) {
                const float Pj = aggP[j * 512 + chb + k];
                const float Lj = aggL[j * 512 + chb + k];
                La[k] = fmaf(Pa[k], Lj, La[k]);
                Pa[k] *= Pj;
            }
            --j;
            if (j < 0) {
                #pragma unroll
                for (int k = 0; k < 4; ++k) C[k] = La[k];
                break;
            }
            __syncthreads();   // st stable before next tid0 write
        }
        // publish inclusive prefix V_b = P_b*C + L_b
        #pragma unroll
        for (int k = 0; k < 4; ++k) pref[b * 512 + chb + k] = fmaf(p[k], C[k], c[k]);
        __threadfence();
        __syncthreads();
        if (c4 == 0)
            __hip_atomic_store(&status[b], 2, __ATOMIC_RELEASE, __HIP_MEMORY_SCOPE_AGENT);
    }

    // phase 2: replay with carry, write h = o*c (float4 stores)
    float cc[4] = {C[0], C[1], C[2], C[3]};
    float h[4]  = {0.f, 0.f, 0.f, 0.f};
    float4* outp = reinterpret_cast<float4*>(out + (long long)b * LC * 512) + c4;
    for (int t = 0; t < LC; ++t) {
        const unsigned short* row = base + t * H3;
        const ushort4 uz = *reinterpret_cast<const ushort4*>(row);
        const ushort4 uf = *reinterpret_cast<const ushort4*>(row + 512);
        const ushort4 uo = *reinterpret_cast<const ushort4*>(row + 1024);
        const float z[4] = {bf2f(uz.x), bf2f(uz.y), bf2f(uz.z), bf2f(uz.w)};
        const float f[4] = {bf2f(uf.x), bf2f(uf.y), bf2f(uf.z), bf2f(uf.w)};
        const float o[4] = {bf2f(uo.x), bf2f(uo.y), bf2f(uo.z), bf2f(uo.w)};
        #pragma unroll
        for (int j = 0; j < 4; ++j) {
            cc[j] = fmaf(f[j], cc[j] - z[j], z[j]);
            h[j]  = o[j] * cc[j];
        }
        float4 hv; hv.x = h[0]; hv.y = h[1]; hv.z = h[2]; hv.w = h[3];
        outp[t * 128] = hv;
    }
    if (b == NCHUNK - 1) {
        #pragma unroll
        for (int j = 0; j < 4; ++j) {
            out[(long long)T_LEN * 512 + chb + j]       = h[j];    // hiddens[-1]
            out[(long long)T_LEN * 512 + 512 + chb + j] = cc[j];   // cells[-1]
        }
    }
}

extern "C" void kernel_launch(void* const* d_in, const int* in_sizes, int n_in,
                              void* d_out, int out_size, void* d_ws, size_t ws_size,
                              hipStream_t stream) {
    const float* x = (const float*)d_in[0];   // [65536, 512]
    const float* W = (const float*)d_in[1];   // [1024, 1536]
    const float* b = (const float*)d_in[2];   // [1536]
    float* out = (float*)d_out;

    char* ws = (char*)d_ws;
    unsigned short* xp  = (unsigned short*)(ws);                 // 67,109,888 B (+pad)
    unsigned short* Wt  = (unsigned short*)(ws + 67110912LL);    // 3,145,728 B
    unsigned short* zfo = (unsigned short*)(ws + 70256640LL);    // 201,326,592 B
    // scan buffers overlay the xp region (dead after GEMM); written only
    // after gemm completes (stream order). status zeroed after gemm launch.
    int*   status = (int*)(ws);                                  // 4 KiB
    float* aggP   = (float*)(ws + 1048576LL);                    // 2 MiB
    float* aggL   = (float*)(ws + 3145728LL);                    // 2 MiB
    float* pref   = (float*)(ws + 5242880LL);                    // 2 MiB

    prep_x<<<4096, 256, 0, stream>>>(x, xp);
    prep_w<<<768, 256, 0, stream>>>(W, Wt);

    dim3 gg(H3 / 256, T_LEN / 128, 1);     // 6 x 512 = 3072 blocks
    gemm_gates<<<gg, 256, 0, stream>>>(xp, Wt, b, zfo);

    hipMemsetAsync(status, 0, NCHUNK * sizeof(int), stream);   // after gemm: xp dead

    scan_fused<<<NCHUNK, 128, 0, stream>>>(zfo, aggP, aggL, pref, status, out);
}

// Round 13
// 369.804 us; speedup vs baseline: 2.3728x; 2.3728x over previous
//
#include <hip/hip_runtime.h>

// QRNN fo-pool: T=65536, E=512, H=512 (kernel_size=2)
// gates[T,1536] = concat(x, shift(x)) @ W + b ; z=tanh, f,o=sigmoid
// c_t = f_t c_{t-1} + (1-f_t) z_t ; h_t = o_t c_t
// out = [hiddens (T*512) | h_last (512) | c_last (512)]  (f32)

#define T_LEN 65536
#define H3    1536
#define LC    128
#define NCHUNK 512

typedef float f32x4 __attribute__((ext_vector_type(4)));
typedef short bf16x8 __attribute__((ext_vector_type(8)));

__device__ __forceinline__ unsigned short f2bf(float f) {
    unsigned int x = __builtin_bit_cast(unsigned int, f);
    x += 0x7fffu + ((x >> 16) & 1u);
    return (unsigned short)(x >> 16);
}
__device__ __forceinline__ float bf2f(unsigned short u) {
    return __builtin_bit_cast(float, ((unsigned int)u) << 16);
}
// fast sigmoid/tanh: v_exp_f32 (exp2) + v_rcp_f32, ~1ulp each — far below bf16 grid
__device__ __forceinline__ float fsig(float x) {
    return __builtin_amdgcn_rcpf(1.f + __builtin_amdgcn_exp2f(-1.44269504f * x));
}
__device__ __forceinline__ float ftanh(float x) {
    return 2.f * __builtin_amdgcn_rcpf(1.f + __builtin_amdgcn_exp2f(-2.88539008f * x)) - 1.f;
}

__device__ __forceinline__ void gload_lds16(const void* g, void* l) {
    __builtin_amdgcn_global_load_lds((const __attribute__((address_space(1))) void*)g,
                                     (__attribute__((address_space(3))) void*)l, 16, 0, 0);
}

#define VM6()   asm volatile("s_waitcnt vmcnt(6)" ::: "memory")
#define VM0()   asm volatile("s_waitcnt vmcnt(0)" ::: "memory")
#define BARX()  __builtin_amdgcn_s_barrier()

// ---- prep (merged): W -> Wt (bf16, transposed) and x -> xp (bf16, zero-prefix)
__global__ void prep_all(const float* __restrict__ x, const float* __restrict__ W,
                         unsigned short* __restrict__ xp, unsigned short* __restrict__ Wt) {
    if (blockIdx.x < 768) {
        // W [1024,1536] f32 -> Wt [1536,1024] bf16
        const int n_el = 1024 * H3;
        for (int i = blockIdx.x * blockDim.x + threadIdx.x; i < n_el;
             i += 768 * blockDim.x) {
            const int k = i / H3, n = i - k * H3;
            Wt[n * 1024 + k] = f2bf(W[i]);
        }
    } else {
        // x (f32) -> bf16 with 512-element zero prefix
        const int bx = blockIdx.x - 768;
        const long long nq = (512LL + (long long)T_LEN * 512) / 4;
        for (long long q = (long long)bx * blockDim.x + threadIdx.x; q < nq;
             q += 4096LL * blockDim.x) {
            ushort4 u;
            if (q < 128) {
                u.x = 0; u.y = 0; u.z = 0; u.w = 0;
            } else {
                const float4 v = *reinterpret_cast<const float4*>(x + q * 4 - 512);
                u.x = f2bf(v.x); u.y = f2bf(v.y); u.z = f2bf(v.z); u.w = f2bf(v.w);
            }
            *reinterpret_cast<ushort4*>(xp + q * 4) = u;
        }
    }
}

// ---- GEMM: 128Mx256N tile, BK=32, 4 waves of 64x128, depth-2 pipeline ----
// (Round-7 kernel, verbatim: best measured 253 µs / MfmaUtil 37%.)
__global__ __launch_bounds__(256, 2) void gemm_gates(
    const unsigned short* __restrict__ xp,
    const unsigned short* __restrict__ Wt,
    const float* __restrict__ bias,
    unsigned short* __restrict__ zfo)
{
    __shared__ unsigned short Alds[3][128 * 32];
    __shared__ unsigned short Blds[3][256 * 32];

    const int tid  = threadIdx.x;
    const int lane = tid & 63;
    const int w    = tid >> 6;           // wave 0..3
    const int wm   = w >> 1, wn = w & 1; // 2x2 wave grid, each 64M x 128N

    // XCD-chunked swizzle (T1): 3072 blocks, 384/XCD; the 6 blocks sharing
    // an A-panel land consecutively on ONE XCD; B (3 MB) L2-resident.
    const int flat = blockIdx.y * gridDim.x + blockIdx.x;   // 0..3071
    const int idx  = (flat & 7) * 384 + (flat >> 3);
    const int nb   = (idx % 6) * 256;                       // N base (0..1280)
    const long long t0 = (long long)(idx / 6) * 128;        // M base (time rows)

    // staging geometry: wave-uniform LDS dest + lane*16B; pre-swizzled source col
    const int srow_l = lane >> 2;                               // 0..15
    const int scol   = (((lane & 3) ^ ((lane >> 3) & 3)) * 8);  // swizzled col (elems)

    const unsigned short* gA = xp + (t0 + w * 16 + srow_l) * 512 + 512 + scol;
    const unsigned short* gB = Wt + (long long)(nb + w * 16 + srow_l) * 1024 + scol;

    auto stage = [&](unsigned short* Al, unsigned short* Bl) {
        gload_lds16(gA,              Al + (w * 16) * 32);
        gload_lds16(gA + 64 * 512,   Al + (64 + w * 16) * 32);
        gload_lds16(gB,              Bl + (w * 16) * 32);
        gload_lds16(gB + 64 * 1024,  Bl + (64 + w * 16) * 32);
        gload_lds16(gB + 128 * 1024, Bl + (128 + w * 16) * 32);
        gload_lds16(gB + 192 * 1024, Bl + (192 + w * 16) * 32);
    };

    // fragment read geometry (swizzled read matches staged involution)
    const int arow  = lane & 15;
    const int swzco = (((lane >> 4) ^ ((arow >> 1) & 3)) * 8);

    f32x4 acc[4][8] = {};

    auto compute = [&](const unsigned short* Al, const unsigned short* Bl) {
        bf16x8 af[4], bfr[8];
        #pragma unroll
        for (int m = 0; m < 4; ++m)
            af[m] = *reinterpret_cast<const bf16x8*>(Al + (wm * 64 + m * 16 + arow) * 32 + swzco);
        #pragma unroll
        for (int n = 0; n < 8; ++n)
            bfr[n] = *reinterpret_cast<const bf16x8*>(Bl + (wn * 128 + n * 16 + arow) * 32 + swzco);
        #pragma unroll
        for (int n = 0; n < 8; ++n)
            #pragma unroll
            for (int m = 0; m < 4; ++m)
                acc[m][n] = __builtin_amdgcn_mfma_f32_16x16x32_bf16(af[m], bfr[n], acc[m][n], 0, 0, 0);
    };

    // prologue: stage tiles 0 (buf0), 1 (buf1); wait 6 oldest = tile0 done
    stage(Alds[0], Blds[0]); gA += 32; gB += 32;
    stage(Alds[1], Blds[1]); gA += 32; gB += 32;
    VM6();
    BARX();

    // main: kt = 0..29 in groups of 3 (buffer indices compile-time)
    for (int kt = 0; kt < 30; kt += 3) {
        {   // kt: stages tile kt+2 -> buf2; computes buf0
            stage(Alds[2], Blds[2]);
            gA += (kt + 2 == 15) ? -992 : 32;  gB += 32;
            compute(Alds[0], Blds[0]);
            VM6();                                            // tile kt+1 landed
            BARX();
        }
        {   // kt+1: stages tile kt+3 -> buf0; computes buf1
            stage(Alds[0], Blds[0]);
            gA += (kt + 3 == 15) ? -992 : 32;  gB += 32;
            compute(Alds[1], Blds[1]);
            VM6();
            BARX();
        }
        {   // kt+2: stages tile kt+4 -> buf1; computes buf2
            stage(Alds[1], Blds[1]);
            gA += (kt + 4 == 15) ? -992 : 32;  gB += 32;
            compute(Alds[2], Blds[2]);
            VM6();
            BARX();
        }
    }
    // kt=30: compute buf0 (tile30); drain tile31; kt=31: compute buf1
    compute(Alds[0], Blds[0]);
    VM0();
    BARX();
    compute(Alds[1], Blds[1]);

    // epilogue: bias + activation (cls uniform per block: nb multiple of 256)
    const int cls = nb >> 9;             // 0=z(tanh), 1=f, 2=o (sigmoid)
    #pragma unroll
    for (int n = 0; n < 8; ++n) {
        const int col = nb + wn * 128 + n * 16 + arow;
        const float bn_ = bias[col];
        #pragma unroll
        for (int m = 0; m < 4; ++m) {
            const long long row0 = t0 + wm * 64 + m * 16 + (lane >> 4) * 4;
            #pragma unroll
            for (int j = 0; j < 4; ++j) {
                float v = acc[m][n][j] + bn_;
                v = (cls == 0) ? ftanh(v) : fsig(v);
                zfo[(row0 + j) * H3 + col] = f2bf(v);
            }
        }
    }
}

// ---- scan pass 1: per-chunk local scan (c_init=0) + product of f ---------
__global__ void scan_pass1(const unsigned short* __restrict__ zfo,
                           float* __restrict__ P, float* __restrict__ L) {
    const int chunk = blockIdx.x;
    const int c4    = threadIdx.x;           // 0..127
    const unsigned short* base = zfo + (long long)chunk * LC * H3 + c4 * 4;
    float c[4] = {0.f, 0.f, 0.f, 0.f};
    float p[4] = {1.f, 1.f, 1.f, 1.f};
    for (int t = 0; t < LC; ++t) {
        const unsigned short* row = base + t * H3;
        const ushort4 uz = *reinterpret_cast<const ushort4*>(row);
        const ushort4 uf = *reinterpret_cast<const ushort4*>(row + 512);
        const float z[4] = {bf2f(uz.x), bf2f(uz.y), bf2f(uz.z), bf2f(uz.w)};
        const float f[4] = {bf2f(uf.x), bf2f(uf.y), bf2f(uf.z), bf2f(uf.w)};
        #pragma unroll
        for (int j = 0; j < 4; ++j) {
            c[j] = fmaf(f[j], c[j] - z[j], z[j]);   // f*c + (1-f)*z
            p[j] *= f[j];
        }
    }
    #pragma unroll
    for (int j = 0; j < 4; ++j) {
        P[chunk * 512 + c4 * 4 + j] = p[j];
        L[chunk * 512 + c4 * 4 + j] = c[j];
    }
}

// ---- scan pass 2: parallel affine-composition scan over chunks -----------
__global__ __launch_bounds__(512) void scan_pass2(
    const float* __restrict__ P, const float* __restrict__ L,
    float* __restrict__ carry, float* __restrict__ out) {
    const int ch = blockIdx.x;
    const int k  = threadIdx.x;              // 0..511 chunks
    __shared__ float sP[NCHUNK], sL[NCHUNK];
    float p = P[k * 512 + ch];
    float l = L[k * 512 + ch];
    sP[k] = p; sL[k] = l;
    __syncthreads();
    for (int d = 1; d < NCHUNK; d <<= 1) {
        float pp = 1.f, ll = 0.f;
        if (k >= d) { pp = sP[k - d]; ll = sL[k - d]; }
        __syncthreads();
        l = fmaf(p, ll, l);
        p = p * pp;
        sP[k] = p; sL[k] = l;
        __syncthreads();
    }
    carry[k * 512 + ch] = (k == 0) ? 0.f : sL[k - 1];
    if (k == NCHUNK - 1) out[(long long)T_LEN * 512 + 512 + ch] = l;   // cells[-1]
}

// ---- scan pass 3: replay with carry-in, write h = o*c (nt f32x4 stores) ---
__global__ void scan_pass3(const unsigned short* __restrict__ zfo,
                           const float* __restrict__ carry,
                           float* __restrict__ out) {
    const int chunk = blockIdx.x;
    const int c4    = threadIdx.x;           // 0..127
    const unsigned short* base = zfo + (long long)chunk * LC * H3 + c4 * 4;
    float c[4], h[4] = {0.f, 0.f, 0.f, 0.f};
    #pragma unroll
    for (int j = 0; j < 4; ++j) c[j] = carry[chunk * 512 + c4 * 4 + j];
    f32x4* outp = reinterpret_cast<f32x4*>(out + (long long)chunk * LC * 512) + c4;
    for (int t = 0; t < LC; ++t) {
        const unsigned short* row = base + t * H3;
        const ushort4 uz = *reinterpret_cast<const ushort4*>(row);
        const ushort4 uf = *reinterpret_cast<const ushort4*>(row + 512);
        const ushort4 uo = *reinterpret_cast<const ushort4*>(row + 1024);
        const float z[4] = {bf2f(uz.x), bf2f(uz.y), bf2f(uz.z), bf2f(uz.w)};
        const float f[4] = {bf2f(uf.x), bf2f(uf.y), bf2f(uf.z), bf2f(uf.w)};
        const float o[4] = {bf2f(uo.x), bf2f(uo.y), bf2f(uo.z), bf2f(uo.w)};
        #pragma unroll
        for (int j = 0; j < 4; ++j) {
            c[j] = fmaf(f[j], c[j] - z[j], z[j]);
            h[j] = o[j] * c[j];
        }
        f32x4 hv = {h[0], h[1], h[2], h[3]};
        __builtin_nontemporal_store(hv, outp + t * 128);   // streamed, never re-read
    }
    if (chunk == NCHUNK - 1) {
        #pragma unroll
        for (int j = 0; j < 4; ++j)
            out[(long long)T_LEN * 512 + c4 * 4 + j] = h[j];     // hiddens[-1]
    }
}

extern "C" void kernel_launch(void* const* d_in, const int* in_sizes, int n_in,
                              void* d_out, int out_size, void* d_ws, size_t ws_size,
                              hipStream_t stream) {
    const float* x = (const float*)d_in[0];   // [65536, 512]
    const float* W = (const float*)d_in[1];   // [1024, 1536]
    const float* b = (const float*)d_in[2];   // [1536]
    float* out = (float*)d_out;

    char* ws = (char*)d_ws;
    unsigned short* xp  = (unsigned short*)(ws);                 // 67,109,888 B (+pad)
    unsigned short* Wt  = (unsigned short*)(ws + 67110912LL);    // 3,145,728 B
    unsigned short* zfo = (unsigned short*)(ws + 70256640LL);    // 201,326,592 B
    // P/L/carry reuse the xp region (dead after GEMM)
    float* P     = (float*)(ws);                                 // 1 MiB each
    float* L     = (float*)(ws + 2097152LL);
    float* carry = (float*)(ws + 4194304LL);

    prep_all<<<768 + 4096, 256, 0, stream>>>(x, W, xp, Wt);

    dim3 gg(H3 / 256, T_LEN / 128, 1);     // 6 x 512 = 3072 blocks
    gemm_gates<<<gg, 256, 0, stream>>>(xp, Wt, b, zfo);

    scan_pass1<<<NCHUNK, 128, 0, stream>>>(zfo, P, L);
    scan_pass2<<<512, NCHUNK, 0, stream>>>(P, L, carry, out);
    scan_pass3<<<NCHUNK, 128, 0, stream>>>(zfo, carry, out);
}